// Round 12
// baseline (213.745 us; speedup 1.0000x reference)
//
#include <hip/hip_runtime.h>
#include <hip/hip_bf16.h>

typedef __attribute__((ext_vector_type(8))) short bf8v;   // 8 x bf16 (4 VGPR)
typedef __attribute__((ext_vector_type(4))) float f4v;    // 4 x f32
typedef __attribute__((ext_vector_type(4))) unsigned u4v;

#define MFMA16(a,b,c) __builtin_amdgcn_mfma_f32_16x16x32_bf16((a),(b),(c),0,0,0)

#define GLD16(gp, lp) __builtin_amdgcn_global_load_lds( \
    (const __attribute__((address_space(1))) void*)(gp), \
    (__attribute__((address_space(3))) void*)(lp), 16, 0, 0)

#define DIMC   1024
#define TSEQ   2048
#define NH     16
#define NKV    4
#define HDIM   64
#define RMS_EPS 1.1920929e-07f
#define QSCALE 0.1803368801111601f   /* 0.125 * log2(e) */

__device__ __forceinline__ ushort f2bf(float f) {
  unsigned u = __builtin_bit_cast(unsigned, f);
  u = (u + 0x7FFFu + ((u >> 16) & 1u)) >> 16;
  return (ushort)u;
}
__device__ __forceinline__ float bf2f(ushort u) {
  return __builtin_bit_cast(float, (unsigned)u << 16);
}
__device__ __forceinline__ unsigned cvtpk(float lo, float hi) {
  unsigned r;
  asm("v_cvt_pk_bf16_f32 %0, %1, %2" : "=v"(r) : "v"(lo), "v"(hi));
  return r;
}

// ------- fused prep: x rmsnorm hi/lo + bf16 copy, weight hi/lo split,
//         Wv/Wp plain, rope tables. blocks 0..4095 = x, 4096.. = weights.
__global__ __launch_bounds__(256) void prep_all(
    const float* __restrict__ x,
    const float* __restrict__ Wq, const float* __restrict__ Wk,
    const float* __restrict__ Wv, const float* __restrict__ Wp,
    ushort* __restrict__ xhi, ushort* __restrict__ xlo,
    ushort* __restrict__ xb,
    ushort* __restrict__ wqkh, ushort* __restrict__ wqkl,
    ushort* __restrict__ wvb, ushort* __restrict__ wpb,
    float* __restrict__ cosT, float* __restrict__ sinT) {
  __shared__ float red[4];
  int bid = blockIdx.x, tid = threadIdx.x;
  if (bid < 4096) {                      // ---- prep_x ----
    int row = bid;
    int lane = tid & 63, w = tid >> 6;
    float4 v = ((const float4*)(x + (size_t)row * DIMC))[tid];
    float ss = v.x * v.x + v.y * v.y + v.z * v.z + v.w * v.w;
    for (int off = 32; off; off >>= 1) ss += __shfl_xor(ss, off);
    if (lane == 0) red[w] = ss;
    __syncthreads();
    float tot = red[0] + red[1] + red[2] + red[3];
    float rs = rsqrtf(tot * (1.0f / DIMC) + RMS_EPS);
    float n0 = v.x * rs, n1 = v.y * rs, n2 = v.z * rs, n3 = v.w * rs;
    ushort4 h, l, ob;
    h.x = f2bf(n0); l.x = f2bf(n0 - bf2f(h.x));
    h.y = f2bf(n1); l.y = f2bf(n1 - bf2f(h.y));
    h.z = f2bf(n2); l.z = f2bf(n2 - bf2f(h.z));
    h.w = f2bf(n3); l.w = f2bf(n3 - bf2f(h.w));
    ob.x = f2bf(v.x); ob.y = f2bf(v.y); ob.z = f2bf(v.z); ob.w = f2bf(v.w);
    ((ushort4*)(xhi + (size_t)row * DIMC))[tid] = h;
    ((ushort4*)(xlo + (size_t)row * DIMC))[tid] = l;
    ((ushort4*)(xb  + (size_t)row * DIMC))[tid] = ob;
    return;
  }
  int wb = bid - 4096;
  if (wb < 1280) {                       // hi/lo split (Wq: 1024 blk, Wk: 256)
    const float* src;
    size_t si, di;
    if (wb < 1024) { src = Wq; si = (size_t)wb * 256 + tid; di = si; }
    else { src = Wk; si = (size_t)(wb - 1024) * 256 + tid; di = 262144 + si; }
    float4 v = ((const float4*)src)[si];
    ushort4 h, l;
    h.x = f2bf(v.x); l.x = f2bf(v.x - bf2f(h.x));
    h.y = f2bf(v.y); l.y = f2bf(v.y - bf2f(h.y));
    h.z = f2bf(v.z); l.z = f2bf(v.z - bf2f(h.z));
    h.w = f2bf(v.w); l.w = f2bf(v.w - bf2f(h.w));
    ((ushort4*)wqkh)[di] = h;
    ((ushort4*)wqkl)[di] = l;
  } else if (wb < 2560) {               // plain (Wv: 256 blk, Wp: 1024)
    const float* src;
    ushort* dst;
    int i;
    if (wb < 1536) { src = Wv; dst = wvb; i = (wb - 1280) * 256 + tid; }
    else           { src = Wp; dst = wpb; i = (wb - 1536) * 256 + tid; }
    float4 v = ((const float4*)src)[i];
    ushort4 o;
    o.x = f2bf(v.x); o.y = f2bf(v.y); o.z = f2bf(v.z); o.w = f2bf(v.w);
    ((ushort4*)dst)[i] = o;
  } else {                               // rope tables (256 blk)
    int i = (wb - 2560) * 256 + tid;     // 65536 = 2048*32
    int t = i >> 5, j = i & 31;
    float inv = 1.0f / powf(10000.0f, (float)j * (1.0f / 32.0f));
    float f = (float)t * inv;
    cosT[i] = cosf(f);
    sinT[i] = sinf(f);
  }
}

// ------- merged QKV projection GEMM, uniform-work seg-split --------------
__global__ __launch_bounds__(256, 3)
void gemm_qkv(const ushort* __restrict__ xhi, const ushort* __restrict__ xlo,
              const ushort* __restrict__ wqkh, const ushort* __restrict__ wqkl,
              float* __restrict__ QKf, ushort* __restrict__ QKc,
              const ushort* __restrict__ xb, const ushort* __restrict__ wvb,
              float* __restrict__ Vf) {
  __shared__ __align__(16) ushort lA[128 * 64];
  __shared__ __align__(16) ushort lB[128 * 64];
  const int bid = blockIdx.x;
  int u;
  bool big;
  if (bid < 256)      { big = true;  u = bid; }
  else if (bid < 448) { big = false; u = bid - 256; }
  else if (bid < 512) { big = true;  u = 256 + (bid - 448); }
  else                { big = false; u = 192 + (bid - 512); }

  const ushort *Ap0, *Bp0, *Ap1, *Bp1;
  float* Cf = QKf;
  int N = 1280, nsteps, mt, n0;
  if (big) {                 // seg1+seg2 partial -> QKc
    mt = u / 10; n0 = (u % 10) * 128;
    Ap0 = xlo; Bp0 = wqkh; Ap1 = xhi; Bp1 = wqkl; nsteps = 32;
  } else if (u < 320) {      // seg0 -> QKf
    mt = u / 10; n0 = (u % 10) * 128;
    Ap0 = xhi; Bp0 = wqkh; Ap1 = Ap0; Bp1 = Bp0; nsteps = 16;
  } else {                   // V -> Vf
    int v = u - 320; mt = v >> 1; n0 = (v & 1) * 128;
    Ap0 = xb; Bp0 = wvb; Ap1 = Ap0; Bp1 = Bp0; nsteps = 16;
    Cf = Vf; N = 256;
  }
  const int m0 = mt * 128;

  const int t = threadIdx.x;
  const int lane = t & 63, w = t >> 6;
  const int wr = w >> 1, wc = w & 1;
  const int l15 = lane & 15, lg = lane >> 4;
  const int srow = t >> 3, scp = t & 7;

  f4v acc[4][4] = {};

  for (int s = 0; s < nsteps; ++s) {
    const ushort* Ab = (s < 16) ? Ap0 : Ap1;
    const ushort* Bb = (s < 16) ? Bp0 : Bp1;
    const int kk = (s & 15) * 64;
    for (int i = 0; i < 4; ++i) {
      int row = srow + i * 32;
      int sc = scp ^ (row & 7);
      const ushort* ga = Ab + (size_t)(m0 + row) * DIMC + kk + sc * 8;
      const ushort* gb = Bb + (size_t)(n0 + row) * DIMC + kk + sc * 8;
      GLD16(ga, &lA[w * 512 + i * 2048]);
      GLD16(gb, &lB[w * 512 + i * 2048]);
    }
    __syncthreads();
    for (int kx = 0; kx < 2; ++kx) {
      bf8v af[4], bfr[4];
      for (int m = 0; m < 4; ++m) {
        int row = wr * 64 + m * 16 + l15;
        int ch = (kx * 4 + lg) ^ (row & 7);
        af[m] = *(const bf8v*)&lA[row * 64 + ch * 8];
      }
      for (int n = 0; n < 4; ++n) {
        int row = wc * 64 + n * 16 + l15;
        int ch = (kx * 4 + lg) ^ (row & 7);
        bfr[n] = *(const bf8v*)&lB[row * 64 + ch * 8];
      }
      for (int m = 0; m < 4; ++m)
        for (int n = 0; n < 4; ++n)
          acc[m][n] = MFMA16(af[m], bfr[n], acc[m][n]);
    }
    __syncthreads();
  }

  if (big) {
    for (int m = 0; m < 4; ++m)
      for (int n = 0; n < 4; ++n)
        for (int j = 0; j < 4; ++j) {
          int r = m0 + wr * 64 + m * 16 + lg * 4 + j;
          int c = n0 + wc * 64 + n * 16 + l15;
          QKc[(size_t)r * 1280 + c] = f2bf(acc[m][n][j]);
        }
  } else {
    for (int m = 0; m < 4; ++m)
      for (int n = 0; n < 4; ++n)
        for (int j = 0; j < 4; ++j) {
          int r = m0 + wr * 64 + m * 16 + lg * 4 + j;
          int c = n0 + wc * 64 + n * 16 + l15;
          Cf[(size_t)r * N + c] = acc[m][n][j];
        }
  }
}

// ---------------- bf16 GEMM (final projection), 64x64 tiles --------------
__global__ __launch_bounds__(256, 4)
void gemm_bt(const ushort* __restrict__ A0, const ushort* __restrict__ B0,
             float* __restrict__ C, int N) {
  __shared__ __align__(16) ushort lA[64 * 64];    // 8 KB
  __shared__ __align__(16) ushort lB[64 * 64];    // 8 KB
  const int t = threadIdx.x;
  const int lane = t & 63, w = t >> 6;
  const int l15 = lane & 15, lg = lane >> 4;
  const int m0 = blockIdx.y * 64, n0 = blockIdx.x * 64;
  const int srow = t >> 3, scp = t & 7;

  f4v acc[4] = {};

  for (int k0 = 0; k0 < 1024; k0 += 64) {
    for (int i = 0; i < 2; ++i) {
      int row = srow + i * 32;
      int sc = scp ^ (row & 7);
      GLD16(A0 + (size_t)(m0 + row) * DIMC + k0 + sc * 8,
            &lA[w * 512 + i * 2048]);
      GLD16(B0 + (size_t)(n0 + row) * DIMC + k0 + sc * 8,
            &lB[w * 512 + i * 2048]);
    }
    __syncthreads();
    for (int kx = 0; kx < 2; ++kx) {
      int arow = w * 16 + l15;
      int ach = (kx * 4 + lg) ^ (arow & 7);
      bf8v af = *(const bf8v*)&lA[arow * 64 + ach * 8];
      for (int n = 0; n < 4; ++n) {
        int row = n * 16 + l15;
        int ch = (kx * 4 + lg) ^ (row & 7);
        bf8v bfr = *(const bf8v*)&lB[row * 64 + ch * 8];
        acc[n] = MFMA16(af, bfr, acc[n]);
      }
    }
    __syncthreads();
  }

  for (int n = 0; n < 4; ++n)
    for (int j = 0; j < 4; ++j) {
      int r = m0 + w * 16 + lg * 4 + j;
      int c = n0 + n * 16 + l15;
      C[(size_t)r * N + c] = acc[n][j];
    }
}

// ---------------- fused post: per-head rms+rope+gain (blocks 0..4095),
//                  V transpose + normalize (blocks 4096..4351) ------------
__global__ __launch_bounds__(256) void post_all(
    const float* __restrict__ QKf, const ushort* __restrict__ QKc,
    const float* __restrict__ cosT,
    const float* __restrict__ sinT, const float* __restrict__ qgain,
    ushort* __restrict__ qhi, ushort* __restrict__ qlo,
    ushort* __restrict__ kb16,
    const float* __restrict__ Vf, ushort* __restrict__ vt2,
    ushort* __restrict__ vhat_q) {
  __shared__ float lds[64][69];
  __shared__ float rnv[64];
  int bid = blockIdx.x;
  if (bid < 4096) {                      // ---- qkv_post ----
    int m = bid;
    int b = m >> 11, tpos = m & 2047;
    int lane = threadIdx.x & 63, w = threadIdx.x >> 6;
    int d = lane, j = d & 31;
    float sgn = (d < 32) ? 1.0f : -1.0f;
    float c = cosT[tpos * 32 + j], s = sinT[tpos * 32 + j];

    for (int i = 0; i < 4; ++i) {
      int h = w * 4 + i;
      size_t base = (size_t)m * 1280 + h * HDIM + d;
      float q = QKf[base] + bf2f(QKc[base]);
      float ss = q * q;
      for (int off = 32; off; off >>= 1) ss += __shfl_xor(ss, off);
      float rs = rsqrtf(ss * (1.0f / HDIM) + RMS_EPS);
      float qn = q * rs;
      float partner = __shfl_xor(qn, 32);
      float ro = (qn * c + sgn * partner * s) * (qgain[h] * QSCALE);
      ushort hi = f2bf(ro);
      ushort lo = f2bf(ro - bf2f(hi));
      size_t idx = (((size_t)b * NH + h) * TSEQ + tpos) * HDIM + d;
      qhi[idx] = hi;
      qlo[idx] = lo;
    }
    {
      int kv = w;
      size_t base = (size_t)m * 1280 + 1024 + kv * HDIM + d;
      float k = QKf[base] + bf2f(QKc[base]);
      float ss = k * k;
      for (int off = 32; off; off >>= 1) ss += __shfl_xor(ss, off);
      float rs = rsqrtf(ss * (1.0f / HDIM) + RMS_EPS);
      float kn = k * rs;
      float partner = __shfl_xor(kn, 32);
      float ro = kn * c + sgn * partner * s;
      kb16[((size_t)(b * NKV + kv) * TSEQ + tpos) * HDIM + d] = f2bf(ro);
    }
    return;
  }
  {                                      // ---- vtrans ----
    int vb = bid - 4096;                 // 256 = 8 bkv * 32 ttile
    int bkv = vb >> 5, tt = vb & 31;
    int b = bkv >> 2, kv = bkv & 3;
    int tid = threadIdx.x;
    for (int i = 0; i < 16; ++i) {
      int idx = i * 256 + tid;
      int tloc = idx >> 6, d = idx & 63;
      lds[d][tloc] = Vf[((size_t)(b * TSEQ + tt * 64 + tloc)) * 256 + kv * 64 + d];
    }
    __syncthreads();
    {
      int t = tid >> 2, prt = tid & 3;
      float ssum = 0.f;
      for (int dd = 0; dd < 16; ++dd) {
        float v = lds[prt * 16 + dd][t];
        ssum += v * v;
      }
      ssum += __shfl_xor(ssum, 1);
      ssum += __shfl_xor(ssum, 2);
      if (prt == 0) rnv[t] = 1.0f / fmaxf(sqrtf(ssum), 1e-12f);
    }
    __syncthreads();
    for (int i = 0; i < 16; ++i) {
      int idx = i * 256 + tid;
      int d = idx >> 6, tloc = idx & 63;
      vt2[(size_t)bkv * (TSEQ * 64) + tt * 4096 + d * 64 + tloc] = f2bf(lds[d][tloc]);
    }
    for (int i = 0; i < 16; ++i) {       // vhat_q: coalesced in d
      int idx = i * 256 + tid;
      int tloc = idx >> 6, d = idx & 63;
      vhat_q[((size_t)bkv * TSEQ + tt * 64 + tloc) * 64 + d] =
          f2bf(lds[d][tloc] * rnv[tloc]);
    }
  }
}

// ---------- causal GQA flash attention, 8-wave 128-q blocks --------------
// 1280 blocks = 32 combos x 40 chunk-slots; 512 threads (8 waves), each
// wave owns 16 q-cols of a 128-row q-tile with the EXACT R8 per-wave
// state (48 VGPR -- the clean version of R7's amortization, no spill).
// K/V staged ONCE per key-tile for all 8 waves (2 GLD16/thread) ->
// block-iters halve (16896 -> 8704) and staging traffic halves.
// Waves 0-3 skip the final diagonal key-tile (wave-uniform branch);
// every chunk has >=1 live tile with >=1 unmasked key per lane (LUT
// verified: kb0 <= 2t for all chunks). launch_bounds(512,8) -> up to
// 4 blocks/CU = 32 waves/CU (vs 20 before).
#define E(s,t,k,l) ((unsigned)(s) | ((unsigned)(t) << 8) | \
                    ((unsigned)(k) << 16) | ((unsigned)(l) << 24))
__global__ __launch_bounds__(512, 8) void attn_chunk(
    const ushort* __restrict__ qhi, const ushort* __restrict__ qlo,
    const ushort* __restrict__ kb16, const ushort* __restrict__ vt2,
    ushort* __restrict__ pyb, float* __restrict__ pml) {
  static const unsigned LUT[40] = {
    // len 8 (13)
    E(36,15,0,8), E(37,15,8,8), E(38,15,16,8), E(39,15,24,8),
    E(32,14,0,8), E(33,14,8,8),
    E(21,11,0,8), E(22,11,8,8), E(23,11,16,8),
    E(18,10,0,8),
    E(10,7,0,8), E(11,7,8,8),
    E(3,3,0,8),
    // len 7 (14)
    E(34,14,16,7), E(35,14,23,7),
    E(28,13,0,7), E(29,13,7,7), E(30,13,14,7), E(31,13,21,7),
    E(24,12,0,7), E(25,12,7,7),
    E(19,10,8,7), E(20,10,15,7),
    E(15,9,0,7), E(16,9,7,7),
    E(8,6,0,7), E(9,6,7,7),
    // len 6 (9)
    E(26,12,14,6), E(27,12,20,6),
    E(17,9,14,6),
    E(12,8,0,6), E(13,8,6,6), E(14,8,12,6),
    E(6,5,0,6), E(7,5,6,6),
    E(2,2,0,6),
    // len 5 (2)
    E(4,4,0,5), E(5,4,5,5),
    // len 4 (1)
    E(1,1,0,4),
    // len 2 (1)
    E(0,0,0,2)
  };
  __shared__ __align__(16) ushort lk[2][64 * 64];    // 16 KB
  __shared__ __align__(16) ushort lv[2][64 * 64];    // 16 KB
  const int t = threadIdx.x;                         // 0..511
  const int lane = t & 63, w = t >> 6;               // w 0..7
  const int bid = blockIdx.x;
  const int combo = bid & 31;
  const unsigned e = LUT[bid >> 5];
  const int slot = e & 255;
  const int tile = (e >> 8) & 31;
  const int kb0 = (e >> 16) & 31;
  const int len = (int)(e >> 24);

  const int xcd = combo & 7, g = (combo >> 3) & 3;
  const int b = xcd >> 2, kv = xcd & 3, h = kv * 4 + g;
  const int l15 = lane & 15, lg = lane >> 4;
  const int q0 = tile * 128 + w * 16;
  const int ktLast = (q0 + 15) >> 6;     // last live key-tile for this wave
  const int srow = t >> 3, sc8 = (t & 7);
  const int rx = l15 & 7;
  const bool odd = (lg & 1);

  const size_t qoff = (((size_t)(b * NH + h)) * TSEQ + q0 + l15) * HDIM;
  bf8v bq0h = *(const bf8v*)(qhi + qoff + lg * 8);
  bf8v bq1h = *(const bf8v*)(qhi + qoff + 32 + lg * 8);
  bf8v bq0l = *(const bf8v*)(qlo + qoff + lg * 8);
  bf8v bq1l = *(const bf8v*)(qlo + qoff + 32 + lg * 8);

  const ushort* kb = kb16 + (size_t)(b * NKV + kv) * TSEQ * 64;
  const ushort* vb = vt2 + (size_t)(b * NKV + kv) * TSEQ * 64;

  // one 8KB K tile + one 8KB V tile staged by 512 threads: 2 GLD16 each
#define STAGE(BUF, KT) do { \
    int sc = sc8 ^ (srow & 7); \
    GLD16(kb + (size_t)((KT) * 64 + srow) * 64 + sc * 8, \
          &lk[BUF][w << 9]); \
    GLD16(vb + (size_t)(KT) * 4096 + srow * 64 + sc * 8, \
          &lv[BUF][w << 9]); \
  } while (0)

  STAGE(0, kb0);

  f4v y[4] = {};
  f4v lsum = {};
  float mrow = 0.f;
  const short ob16 = (short)0x3F80;      // bf16 1.0
  const bf8v onesv = { ob16, ob16, ob16, ob16, ob16, ob16, ob16, ob16 };

#pragma unroll 1
  for (int itc = 0; itc < len; ++itc) {
    const int cur = itc & 1;
    const int kt = kb0 + itc;
    __syncthreads();                       // drains prefetch of buf[cur]
    if (itc + 1 < len) STAGE(cur ^ 1, kt + 1);  // flies under this compute

    if (kt <= ktLast) {                    // wave-uniform causal skip
      const ushort* lkc = &lk[cur][0];
      const ushort* lvc = &lv[cur][0];
      const int kv0 = kt * 64;

      // QK: kh*(qh+ql); C-init = -mrow so scores arrive pre-subtracted
      f4v s4[4];
      const f4v zi = { -mrow, -mrow, -mrow, -mrow };
      __builtin_amdgcn_s_setprio(1);
#pragma unroll
      for (int n = 0; n < 4; ++n) {
        const ushort* krow = lkc + (n * 16 + l15) * 64;
        bf8v kh0 = *(const bf8v*)&krow[((0 + lg) ^ rx) * 8];
        bf8v kh1 = *(const bf8v*)&krow[((4 + lg) ^ rx) * 8];
        f4v acc = MFMA16(kh0, bq0h, zi);
        acc = MFMA16(kh1, bq1h, acc);
        acc = MFMA16(kh0, bq0l, acc);
        acc = MFMA16(kh1, bq1l, acc);
        s4[n] = acc;
      }
      __builtin_amdgcn_s_setprio(0);

      // mask + per-lane max; lane holds (S-mrow)^T[key][q=q0+l15]
      const bool need_mask = (kt == ktLast);
      float mloc = -1e30f;
#pragma unroll
      for (int n = 0; n < 4; ++n)
#pragma unroll
        for (int j = 0; j < 4; ++j) {
          float v = s4[n][j];
          if (need_mask && (kv0 + n * 16 + lg * 4 + j > q0 + l15)) v = -1e30f;
          s4[n][j] = v;
          mloc = fmaxf(mloc, v);
        }
      // vote first (VCC only); cross-lane reduce + adjust only on trigger
      if (__any(mloc > 11.5f)) {
        float mf = fmaxf(mloc, __shfl_xor(mloc, 16));
        mf = fmaxf(mf, __shfl_xor(mf, 32));
        float delta = fmaxf(mf, 0.f);
        float scf = exp2f(-delta);
        lsum *= scf;
#pragma unroll
        for (int n = 0; n < 4; ++n) y[n] *= scf;
#pragma unroll
        for (int n = 0; n < 4; ++n)
#pragma unroll
          for (int j = 0; j < 4; ++j) s4[n][j] -= delta;
        mrow += delta;
      }
#pragma unroll
      for (int n = 0; n < 4; ++n)
#pragma unroll
        for (int j = 0; j < 4; ++j)
          s4[n][j] = exp2f(s4[n][j]);     // arg <= 11.5 by vote invariant

      // ---- in-register P^T redistribution (no LDS, no barrier) ----
      unsigned d0a = cvtpk(s4[0][0], s4[0][1]), d0b = cvtpk(s4[0][2], s4[0][3]);
      unsigned d1a = cvtpk(s4[1][0], s4[1][1]), d1b = cvtpk(s4[1][2], s4[1][3]);
      unsigned d2a = cvtpk(s4[2][0], s4[2][1]), d2b = cvtpk(s4[2][2], s4[2][3]);
      unsigned d3a = cvtpk(s4[3][0], s4[3][1]), d3b = cvtpk(s4[3][2], s4[3][3]);
      asm("v_permlane32_swap_b32 %0, %1" : "+v"(d0a), "+v"(d1a));
      asm("v_permlane32_swap_b32 %0, %1" : "+v"(d0b), "+v"(d1b));
      asm("v_permlane32_swap_b32 %0, %1" : "+v"(d2a), "+v"(d3a));
      asm("v_permlane32_swap_b32 %0, %1" : "+v"(d2b), "+v"(d3b));
      unsigned sa0 = (unsigned)__shfl_xor((int)d0a, 16);
      unsigned sb0 = (unsigned)__shfl_xor((int)d1a, 16);
      unsigned sa1 = (unsigned)__shfl_xor((int)d0b, 16);
      unsigned sb1 = (unsigned)__shfl_xor((int)d1b, 16);
      unsigned sa2 = (unsigned)__shfl_xor((int)d2a, 16);
      unsigned sb2 = (unsigned)__shfl_xor((int)d3a, 16);
      unsigned sa3 = (unsigned)__shfl_xor((int)d2b, 16);
      unsigned sb3 = (unsigned)__shfl_xor((int)d3b, 16);
      u4v u0 = { odd ? sb0 : d0a, odd ? sb1 : d0b,
                 odd ? d1a : sa0, odd ? d1b : sa1 };
      u4v u1 = { odd ? sb2 : d2a, odd ? sb3 : d2b,
                 odd ? d3a : sa2, odd ? d3b : sa3 };
      bf8v pb0 = __builtin_bit_cast(bf8v, u0);
      bf8v pb1 = __builtin_bit_cast(bf8v, u1);

      __builtin_amdgcn_s_setprio(1);
#pragma unroll
      for (int n = 0; n < 4; ++n) {
        const ushort* vrow = lvc + (n * 16 + l15) * 64;
        bf8v va0 = *(const bf8v*)&vrow[((0 + lg) ^ rx) * 8];
        bf8v va1 = *(const bf8v*)&vrow[((4 + lg) ^ rx) * 8];
        y[n] = MFMA16(va0, pb0, y[n]);
        y[n] = MFMA16(va1, pb1, y[n]);
      }
      lsum = MFMA16(onesv, pb0, lsum);   // row-sum on the MFMA pipe
      lsum = MFMA16(onesv, pb1, lsum);
      __builtin_amdgcn_s_setprio(0);
    }
  }
#undef STAGE

  // epilogue: lrow = lsum[0]; write unnormalized y partial bf16 [128][64]
  {
    const float lrow = lsum[0];
    const int pslot = combo * 40 + slot;
    ushort* pb = pyb + (size_t)pslot * 8192;
    const int qp = w * 16 + l15;           // 0..127
#pragma unroll
    for (int n = 0; n < 4; ++n) {
      uint2 pk;
      pk.x = cvtpk(y[n][0], y[n][1]);
      pk.y = cvtpk(y[n][2], y[n][3]);
      *(uint2*)&pb[qp * 64 + n * 16 + lg * 4] = pk;
    }
    if (lane < 16) {
      float* mlp = pml + (size_t)pslot * 256;
      mlp[qp] = mrow;
      mlp[128 + qp] = lrow;
    }
  }
}
#undef E

// -------- combine: merge chunk partials, normalize, v-hat removal --------
// 1024 blocks = 32 combos x 32 q-64-groups (ht); tile = ht>>1, <=4 partials.
__global__ __launch_bounds__(256) void combine_kern(
    const ushort* __restrict__ pyb, const float* __restrict__ pml,
    const ushort* __restrict__ vhat_q, ushort* __restrict__ ytil) {
  const int bid = blockIdx.x;
  const int combo = bid & 31, ht = bid >> 5;
  const int tile = ht >> 1;
  const int xcd = combo & 7, g = (combo >> 3) & 3;
  const int b = xcd >> 2, kv = xcd & 3, h = kv * 4 + g;
  const int nch = (tile >> 2) + 1;
  const int sb = (tile < 4) ? tile
               : (tile < 8) ? 4 + 2 * (tile - 4)
               : (tile < 12) ? 12 + 3 * (tile - 8)
                             : 24 + 4 * (tile - 12);
  const int tid = threadIdx.x;
  const int q = tid >> 2, ds = (tid & 3) * 16;
  const int qp = (ht & 1) * 64 + q;          // row within 128-q partial
  const int q0 = ht * 64;                    // global q base of this block

  float m[4], l[4];
#pragma unroll
  for (int ci = 0; ci < 4; ++ci) {
    if (ci < nch) {
      const float* mlp = pml + (size_t)(combo * 40 + sb + ci) * 256;
      m[ci] = mlp[qp];
      l[ci] = mlp[128 + qp];
    } else { m[ci] = -1e30f; l[ci] = 0.f; }
  }
  float M = fmaxf(fmaxf(m[0], m[1]), fmaxf(m[2], m[3]));
  float y[16] = {};
  float ltot = 0.f;
#pragma unroll
  for (int ci = 0; ci < 4; ++ci) {
    if (ci < nch) {
      float sc = exp2f(m[ci] - M);
      ltot += l[ci] * sc;
      const ushort* pb = pyb + (size_t)(combo * 40 + sb + ci) * 8192 + qp * 64 + ds;
      bf8v p0 = *(const bf8v*)pb;
      bf8v p1 = *(const bf8v*)(pb + 8);
#pragma unroll
      for (int dd = 0; dd < 8; ++dd) {
        y[dd] += sc * bf2f((ushort)p0[dd]);
        y[8 + dd] += sc * bf2f((ushort)p1[dd]);
      }
    }
  }
  float inv = 1.0f / fmaxf(ltot, 1e-37f);   // guard degenerate rows
  const ushort* vh = vhat_q + ((size_t)(b * NKV + kv) * TSEQ + q0 + q) * 64 + ds;
  bf8v v0 = *(const bf8v*)vh;
  bf8v v1 = *(const bf8v*)(vh + 8);
  float vv[16];
  float dp = 0.f;
#pragma unroll
  for (int dd = 0; dd < 8; ++dd) {
    vv[dd] = bf2f((ushort)v0[dd]);
    vv[8 + dd] = bf2f((ushort)v1[dd]);
  }
#pragma unroll
  for (int dd = 0; dd < 16; ++dd) {
    y[dd] *= inv;
    dp += y[dd] * vv[dd];
  }
  dp += __shfl_xor(dp, 1);
  dp += __shfl_xor(dp, 2);
  bf8v o0, o1;
#pragma unroll
  for (int dd = 0; dd < 8; ++dd) {
    o0[dd] = (short)f2bf(y[dd] - dp * vv[dd]);
    o1[dd] = (short)f2bf(y[8 + dd] - dp * vv[8 + dd]);
  }
  ushort* yo = ytil + ((size_t)(b * TSEQ + q0 + q)) * DIMC + h * HDIM + ds;
  *(bf8v*)yo = o0;
  *(bf8v*)(yo + 8) = o1;
}

extern "C" void kernel_launch(void* const* d_in, const int* in_sizes, int n_in,
                              void* d_out, int out_size, void* d_ws, size_t ws_size,
                              hipStream_t stream) {
  (void)in_sizes; (void)n_in; (void)out_size; (void)ws_size;
  const float* x  = (const float*)d_in[0];
  const float* Wq = (const float*)d_in[1];
  const float* Wk = (const float*)d_in[2];
  const float* Wv = (const float*)d_in[3];
  const float* Wp = (const float*)d_in[4];
  const float* qg = (const float*)d_in[5];
  float* out = (float*)d_out;
  char* ws = (char*)d_ws;
  const size_t KB = 1024, MB = 1ull << 20;

  ushort* xhi = (ushort*)(ws);                         // 8 MiB -> qhi
  ushort* xlo = (ushort*)(ws + 8 * MB);                // 8 MiB -> qlo
  ushort* xb  = (ushort*)(ws + 16 * MB);               // 8 MiB -> ytil
  ushort* wqkh = (ushort*)(ws + 24 * MB);              // 2.5 MiB (Wq|Wk hi)
  ushort* wqkl = (ushort*)(ws + 26 * MB + 512 * KB);   // 2.5 MiB (Wq|Wk lo)
  ushort* wvb = (ushort*)(ws + 29 * MB);               // 0.5 MiB
  ushort* wpb = (ushort*)(ws + 29 * MB + 512 * KB);    // 2 MiB
  float*  cosT = (float*)(ws + 31 * MB + 512 * KB);    // 0.25 MiB
  float*  sinT = (float*)(ws + 31 * MB + 768 * KB);    // 0.25 MiB
  float*  QKf  = (float*)(ws + 32 * MB);               // 20 MiB [4096][1280]
  ushort* kb16 = (ushort*)(ws + 52 * MB);              // 2 MiB
  ushort* vt2  = (ushort*)(ws + 54 * MB);              // 2 MiB

  float*  Vf   = out;                            // d_out: 4 MiB (V f32)
  ushort* QKc  = (ushort*)((char*)out + 4 * MB); // d_out: 10 MiB bf16
  ushort* vhat_q = (ushort*)((char*)out + 14 * MB); // d_out: 2 MiB
  ushort* qhb  = xhi;    // reuse after projections
  ushort* qlb  = xlo;
  ushort* ytil = xb;
  // chunk partials overlay dead QKf: 1280*16KB = 20 MiB; ml at 56MB
  ushort* pyb = (ushort*)(ws + 32 * MB);
  float*  pml = (float*)(ws + 56 * MB);          // 1280*1KB = 1.25 MiB

  prep_all<<<6912, 256, 0, stream>>>(x, Wq, Wk, Wv, Wp, xhi, xlo, xb,
                                     wqkh, wqkl, wvb, wpb, cosT, sinT);

  gemm_qkv<<<704, 256, 0, stream>>>(xhi, xlo, wqkh, wqkl, QKf, QKc,
                                    xb, wvb, Vf);

  post_all<<<4352, 256, 0, stream>>>(QKf, QKc, cosT, sinT, qg, qhb, qlb, kb16,
                                     Vf, vt2, vhat_q);
  attn_chunk<<<1280, 512, 0, stream>>>(qhb, qlb, kb16, vt2, pyb, pml);
  combine_kern<<<1024, 256, 0, stream>>>(pyb, pml, vhat_q, ytil);
  gemm_bt<<<dim3(16, 64), 256, 0, stream>>>(ytil, wpb, out, 1024);
}

// Round 13
// 140.108 us; speedup vs baseline: 1.5256x; 1.5256x over previous
//
#include <hip/hip_runtime.h>
#include <hip/hip_bf16.h>

typedef __attribute__((ext_vector_type(8))) short bf8v;   // 8 x bf16 (4 VGPR)
typedef __attribute__((ext_vector_type(4))) float f4v;    // 4 x f32
typedef __attribute__((ext_vector_type(4))) unsigned u4v;

#define MFMA16(a,b,c) __builtin_amdgcn_mfma_f32_16x16x32_bf16((a),(b),(c),0,0,0)

#define GLD16(gp, lp) __builtin_amdgcn_global_load_lds( \
    (const __attribute__((address_space(1))) void*)(gp), \
    (__attribute__((address_space(3))) void*)(lp), 16, 0, 0)

#define DIMC   1024
#define TSEQ   2048
#define NH     16
#define NKV    4
#define HDIM   64
#define RMS_EPS 1.1920929e-07f
#define QSCALE 0.1803368801111601f   /* 0.125 * log2(e) */

__device__ __forceinline__ ushort f2bf(float f) {
  unsigned u = __builtin_bit_cast(unsigned, f);
  u = (u + 0x7FFFu + ((u >> 16) & 1u)) >> 16;
  return (ushort)u;
}
__device__ __forceinline__ float bf2f(ushort u) {
  return __builtin_bit_cast(float, (unsigned)u << 16);
}
__device__ __forceinline__ unsigned cvtpk(float lo, float hi) {
  unsigned r;
  asm("v_cvt_pk_bf16_f32 %0, %1, %2" : "=v"(r) : "v"(lo), "v"(hi));
  return r;
}

// ------- fused prep: x rmsnorm hi/lo + bf16 copy, weight hi/lo split,
//         Wv/Wp plain, rope tables. blocks 0..4095 = x, 4096.. = weights.
__global__ __launch_bounds__(256) void prep_all(
    const float* __restrict__ x,
    const float* __restrict__ Wq, const float* __restrict__ Wk,
    const float* __restrict__ Wv, const float* __restrict__ Wp,
    ushort* __restrict__ xhi, ushort* __restrict__ xlo,
    ushort* __restrict__ xb,
    ushort* __restrict__ wqkh, ushort* __restrict__ wqkl,
    ushort* __restrict__ wvb, ushort* __restrict__ wpb,
    float* __restrict__ cosT, float* __restrict__ sinT) {
  __shared__ float red[4];
  int bid = blockIdx.x, tid = threadIdx.x;
  if (bid < 4096) {                      // ---- prep_x ----
    int row = bid;
    int lane = tid & 63, w = tid >> 6;
    float4 v = ((const float4*)(x + (size_t)row * DIMC))[tid];
    float ss = v.x * v.x + v.y * v.y + v.z * v.z + v.w * v.w;
    for (int off = 32; off; off >>= 1) ss += __shfl_xor(ss, off);
    if (lane == 0) red[w] = ss;
    __syncthreads();
    float tot = red[0] + red[1] + red[2] + red[3];
    float rs = rsqrtf(tot * (1.0f / DIMC) + RMS_EPS);
    float n0 = v.x * rs, n1 = v.y * rs, n2 = v.z * rs, n3 = v.w * rs;
    ushort4 h, l, ob;
    h.x = f2bf(n0); l.x = f2bf(n0 - bf2f(h.x));
    h.y = f2bf(n1); l.y = f2bf(n1 - bf2f(h.y));
    h.z = f2bf(n2); l.z = f2bf(n2 - bf2f(h.z));
    h.w = f2bf(n3); l.w = f2bf(n3 - bf2f(h.w));
    ob.x = f2bf(v.x); ob.y = f2bf(v.y); ob.z = f2bf(v.z); ob.w = f2bf(v.w);
    ((ushort4*)(xhi + (size_t)row * DIMC))[tid] = h;
    ((ushort4*)(xlo + (size_t)row * DIMC))[tid] = l;
    ((ushort4*)(xb  + (size_t)row * DIMC))[tid] = ob;
    return;
  }
  int wb = bid - 4096;
  if (wb < 1280) {                       // hi/lo split (Wq: 1024 blk, Wk: 256)
    const float* src;
    size_t si, di;
    if (wb < 1024) { src = Wq; si = (size_t)wb * 256 + tid; di = si; }
    else { src = Wk; si = (size_t)(wb - 1024) * 256 + tid; di = 262144 + si; }
    float4 v = ((const float4*)src)[si];
    ushort4 h, l;
    h.x = f2bf(v.x); l.x = f2bf(v.x - bf2f(h.x));
    h.y = f2bf(v.y); l.y = f2bf(v.y - bf2f(h.y));
    h.z = f2bf(v.z); l.z = f2bf(v.z - bf2f(h.z));
    h.w = f2bf(v.w); l.w = f2bf(v.w - bf2f(h.w));
    ((ushort4*)wqkh)[di] = h;
    ((ushort4*)wqkl)[di] = l;
  } else if (wb < 2560) {               // plain (Wv: 256 blk, Wp: 1024)
    const float* src;
    ushort* dst;
    int i;
    if (wb < 1536) { src = Wv; dst = wvb; i = (wb - 1280) * 256 + tid; }
    else           { src = Wp; dst = wpb; i = (wb - 1536) * 256 + tid; }
    float4 v = ((const float4*)src)[i];
    ushort4 o;
    o.x = f2bf(v.x); o.y = f2bf(v.y); o.z = f2bf(v.z); o.w = f2bf(v.w);
    ((ushort4*)dst)[i] = o;
  } else {                               // rope tables (256 blk)
    int i = (wb - 2560) * 256 + tid;     // 65536 = 2048*32
    int t = i >> 5, j = i & 31;
    float inv = 1.0f / powf(10000.0f, (float)j * (1.0f / 32.0f));
    float f = (float)t * inv;
    cosT[i] = cosf(f);
    sinT[i] = sinf(f);
  }
}

// ------- merged QKV projection GEMM, uniform-work seg-split --------------
// R8 known-good double-buffer structure (32KB LDS, 3 blocks/CU).
__global__ __launch_bounds__(256, 3)
void gemm_qkv(const ushort* __restrict__ xhi, const ushort* __restrict__ xlo,
              const ushort* __restrict__ wqkh, const ushort* __restrict__ wqkl,
              float* __restrict__ QKf, ushort* __restrict__ QKc,
              const ushort* __restrict__ xb, const ushort* __restrict__ wvb,
              float* __restrict__ Vf) {
  __shared__ __align__(16) ushort lA[128 * 64];
  __shared__ __align__(16) ushort lB[128 * 64];
  const int bid = blockIdx.x;
  int u;
  bool big;
  if (bid < 256)      { big = true;  u = bid; }
  else if (bid < 448) { big = false; u = bid - 256; }
  else if (bid < 512) { big = true;  u = 256 + (bid - 448); }
  else                { big = false; u = 192 + (bid - 512); }

  const ushort *Ap0, *Bp0, *Ap1, *Bp1;
  float* Cf = QKf;
  int N = 1280, nsteps, mt, n0;
  if (big) {                 // seg1+seg2 partial -> QKc
    mt = u / 10; n0 = (u % 10) * 128;
    Ap0 = xlo; Bp0 = wqkh; Ap1 = xhi; Bp1 = wqkl; nsteps = 32;
  } else if (u < 320) {      // seg0 -> QKf
    mt = u / 10; n0 = (u % 10) * 128;
    Ap0 = xhi; Bp0 = wqkh; Ap1 = Ap0; Bp1 = Bp0; nsteps = 16;
  } else {                   // V -> Vf
    int v = u - 320; mt = v >> 1; n0 = (v & 1) * 128;
    Ap0 = xb; Bp0 = wvb; Ap1 = Ap0; Bp1 = Bp0; nsteps = 16;
    Cf = Vf; N = 256;
  }
  const int m0 = mt * 128;

  const int t = threadIdx.x;
  const int lane = t & 63, w = t >> 6;
  const int wr = w >> 1, wc = w & 1;
  const int l15 = lane & 15, lg = lane >> 4;
  const int srow = t >> 3, scp = t & 7;

  f4v acc[4][4] = {};

  for (int s = 0; s < nsteps; ++s) {
    const ushort* Ab = (s < 16) ? Ap0 : Ap1;
    const ushort* Bb = (s < 16) ? Bp0 : Bp1;
    const int kk = (s & 15) * 64;
    for (int i = 0; i < 4; ++i) {
      int row = srow + i * 32;
      int sc = scp ^ (row & 7);
      const ushort* ga = Ab + (size_t)(m0 + row) * DIMC + kk + sc * 8;
      const ushort* gb = Bb + (size_t)(n0 + row) * DIMC + kk + sc * 8;
      GLD16(ga, &lA[w * 512 + i * 2048]);
      GLD16(gb, &lB[w * 512 + i * 2048]);
    }
    __syncthreads();
    for (int kx = 0; kx < 2; ++kx) {
      bf8v af[4], bfr[4];
      for (int m = 0; m < 4; ++m) {
        int row = wr * 64 + m * 16 + l15;
        int ch = (kx * 4 + lg) ^ (row & 7);
        af[m] = *(const bf8v*)&lA[row * 64 + ch * 8];
      }
      for (int n = 0; n < 4; ++n) {
        int row = wc * 64 + n * 16 + l15;
        int ch = (kx * 4 + lg) ^ (row & 7);
        bfr[n] = *(const bf8v*)&lB[row * 64 + ch * 8];
      }
      for (int m = 0; m < 4; ++m)
        for (int n = 0; n < 4; ++n)
          acc[m][n] = MFMA16(af[m], bfr[n], acc[m][n]);
    }
    __syncthreads();
  }

  if (big) {
    for (int m = 0; m < 4; ++m)
      for (int n = 0; n < 4; ++n)
        for (int j = 0; j < 4; ++j) {
          int r = m0 + wr * 64 + m * 16 + lg * 4 + j;
          int c = n0 + wc * 64 + n * 16 + l15;
          QKc[(size_t)r * 1280 + c] = f2bf(acc[m][n][j]);
        }
  } else {
    for (int m = 0; m < 4; ++m)
      for (int n = 0; n < 4; ++n)
        for (int j = 0; j < 4; ++j) {
          int r = m0 + wr * 64 + m * 16 + lg * 4 + j;
          int c = n0 + wc * 64 + n * 16 + l15;
          Cf[(size_t)r * N + c] = acc[m][n][j];
        }
  }
}

// ---------------- bf16 GEMM (final projection), 64x64 tiles --------------
__global__ __launch_bounds__(256, 4)
void gemm_bt(const ushort* __restrict__ A0, const ushort* __restrict__ B0,
             float* __restrict__ C, int N) {
  __shared__ __align__(16) ushort lA[64 * 64];    // 8 KB
  __shared__ __align__(16) ushort lB[64 * 64];    // 8 KB
  const int t = threadIdx.x;
  const int lane = t & 63, w = t >> 6;
  const int l15 = lane & 15, lg = lane >> 4;
  const int m0 = blockIdx.y * 64, n0 = blockIdx.x * 64;
  const int srow = t >> 3, scp = t & 7;

  f4v acc[4] = {};

  for (int k0 = 0; k0 < 1024; k0 += 64) {
    for (int i = 0; i < 2; ++i) {
      int row = srow + i * 32;
      int sc = scp ^ (row & 7);
      GLD16(A0 + (size_t)(m0 + row) * DIMC + k0 + sc * 8,
            &lA[w * 512 + i * 2048]);
      GLD16(B0 + (size_t)(n0 + row) * DIMC + k0 + sc * 8,
            &lB[w * 512 + i * 2048]);
    }
    __syncthreads();
    for (int kx = 0; kx < 2; ++kx) {
      int arow = w * 16 + l15;
      int ach = (kx * 4 + lg) ^ (arow & 7);
      bf8v af = *(const bf8v*)&lA[arow * 64 + ach * 8];
      for (int n = 0; n < 4; ++n) {
        int row = n * 16 + l15;
        int ch = (kx * 4 + lg) ^ (row & 7);
        bf8v bfr = *(const bf8v*)&lB[row * 64 + ch * 8];
        acc[n] = MFMA16(af, bfr, acc[n]);
      }
    }
    __syncthreads();
  }

  for (int n = 0; n < 4; ++n)
    for (int j = 0; j < 4; ++j) {
      int r = m0 + w * 16 + lg * 4 + j;
      int c = n0 + n * 16 + l15;
      C[(size_t)r * N + c] = acc[n][j];
    }
}

// ---------------- fused post: per-head rms+rope+gain (blocks 0..4095),
//                  V transpose + normalize (blocks 4096..4351) ------------
__global__ __launch_bounds__(256) void post_all(
    const float* __restrict__ QKf, const ushort* __restrict__ QKc,
    const float* __restrict__ cosT,
    const float* __restrict__ sinT, const float* __restrict__ qgain,
    ushort* __restrict__ qhi, ushort* __restrict__ qlo,
    ushort* __restrict__ kb16,
    const float* __restrict__ Vf, ushort* __restrict__ vt2,
    ushort* __restrict__ vhat_q) {
  __shared__ float lds[64][69];
  __shared__ float rnv[64];
  int bid = blockIdx.x;
  if (bid < 4096) {                      // ---- qkv_post ----
    int m = bid;
    int b = m >> 11, tpos = m & 2047;
    int lane = threadIdx.x & 63, w = threadIdx.x >> 6;
    int d = lane, j = d & 31;
    float sgn = (d < 32) ? 1.0f : -1.0f;
    float c = cosT[tpos * 32 + j], s = sinT[tpos * 32 + j];

    for (int i = 0; i < 4; ++i) {
      int h = w * 4 + i;
      size_t base = (size_t)m * 1280 + h * HDIM + d;
      float q = QKf[base] + bf2f(QKc[base]);
      float ss = q * q;
      for (int off = 32; off; off >>= 1) ss += __shfl_xor(ss, off);
      float rs = rsqrtf(ss * (1.0f / HDIM) + RMS_EPS);
      float qn = q * rs;
      float partner = __shfl_xor(qn, 32);
      float ro = (qn * c + sgn * partner * s) * (qgain[h] * QSCALE);
      ushort hi = f2bf(ro);
      ushort lo = f2bf(ro - bf2f(hi));
      size_t idx = (((size_t)b * NH + h) * TSEQ + tpos) * HDIM + d;
      qhi[idx] = hi;
      qlo[idx] = lo;
    }
    {
      int kv = w;
      size_t base = (size_t)m * 1280 + 1024 + kv * HDIM + d;
      float k = QKf[base] + bf2f(QKc[base]);
      float ss = k * k;
      for (int off = 32; off; off >>= 1) ss += __shfl_xor(ss, off);
      float rs = rsqrtf(ss * (1.0f / HDIM) + RMS_EPS);
      float kn = k * rs;
      float partner = __shfl_xor(kn, 32);
      float ro = kn * c + sgn * partner * s;
      kb16[((size_t)(b * NKV + kv) * TSEQ + tpos) * HDIM + d] = f2bf(ro);
    }
    return;
  }
  {                                      // ---- vtrans ----
    int vb = bid - 4096;                 // 256 = 8 bkv * 32 ttile
    int bkv = vb >> 5, tt = vb & 31;
    int b = bkv >> 2, kv = bkv & 3;
    int tid = threadIdx.x;
    for (int i = 0; i < 16; ++i) {
      int idx = i * 256 + tid;
      int tloc = idx >> 6, d = idx & 63;
      lds[d][tloc] = Vf[((size_t)(b * TSEQ + tt * 64 + tloc)) * 256 + kv * 64 + d];
    }
    __syncthreads();
    {
      int t = tid >> 2, prt = tid & 3;
      float ssum = 0.f;
      for (int dd = 0; dd < 16; ++dd) {
        float v = lds[prt * 16 + dd][t];
        ssum += v * v;
      }
      ssum += __shfl_xor(ssum, 1);
      ssum += __shfl_xor(ssum, 2);
      if (prt == 0) rnv[t] = 1.0f / fmaxf(sqrtf(ssum), 1e-12f);
    }
    __syncthreads();
    for (int i = 0; i < 16; ++i) {
      int idx = i * 256 + tid;
      int d = idx >> 6, tloc = idx & 63;
      vt2[(size_t)bkv * (TSEQ * 64) + tt * 4096 + d * 64 + tloc] = f2bf(lds[d][tloc]);
    }
    for (int i = 0; i < 16; ++i) {       // vhat_q: coalesced in d
      int idx = i * 256 + tid;
      int tloc = idx >> 6, d = idx & 63;
      vhat_q[((size_t)bkv * TSEQ + tt * 64 + tloc) * 64 + d] =
          f2bf(lds[d][tloc] * rnv[tloc]);
    }
  }
}

// ---------- causal GQA flash attention, key-split chunks (flash-decode) --
// 2560 blocks = 32 combos x 80 chunk-slots (cap 8 key-tiles), 32KB LDS,
// 5 blocks/CU, in-register P redistribution (R8 known-good: 55.0us).
// Structural floor for this decomposition: residency (R5), chain length
// (R4), P-LDS (R6), VALU diet (R8), vmcnt pipeline (R9), wave
// amortization (R7/R12 spill) all nulled or regressed.
#define E(s,t,k,l) ((unsigned)(s) | ((unsigned)(t) << 8) | \
                    ((unsigned)(k) << 16) | ((unsigned)(l) << 24))
__global__ __launch_bounds__(256, 5) void attn_chunk(
    const ushort* __restrict__ qhi, const ushort* __restrict__ qlo,
    const ushort* __restrict__ kb16, const ushort* __restrict__ vt2,
    ushort* __restrict__ pyb, float* __restrict__ pml) {
  static const unsigned LUT[80] = {
    // len 8 (20)
    E(76,31,0,8), E(77,31,8,8), E(78,31,16,8), E(79,31,24,8),
    E(72,30,0,8), E(73,30,8,8), E(74,30,16,8),
    E(68,29,0,8), E(69,29,8,8), E(64,28,0,8),
    E(45,23,0,8), E(46,23,8,8), E(47,23,16,8),
    E(42,22,0,8), E(43,22,8,8), E(39,21,0,8),
    E(22,15,0,8), E(23,15,8,8), E(20,14,0,8), E(7,7,0,8),
    // len 7 (30)
    E(75,30,24,7), E(70,29,16,7), E(71,29,23,7),
    E(65,28,8,7), E(66,28,15,7), E(67,28,22,7),
    E(60,27,0,7), E(61,27,7,7), E(62,27,14,7), E(63,27,21,7),
    E(56,26,0,7), E(57,26,7,7), E(58,26,14,7),
    E(52,25,0,7), E(53,25,7,7), E(48,24,0,7),
    E(44,22,16,7), E(40,21,8,7), E(41,21,15,7),
    E(36,20,0,7), E(37,20,7,7), E(38,20,14,7),
    E(33,19,0,7), E(34,19,7,7), E(30,18,0,7),
    E(21,14,8,7), E(18,13,0,7), E(19,13,7,7), E(16,12,0,7), E(6,6,0,7),
    // len 6 (19)
    E(59,26,21,6), E(54,25,14,6), E(55,25,20,6),
    E(49,24,7,6), E(50,24,13,6), E(51,24,19,6),
    E(35,19,14,6), E(31,18,7,6), E(32,18,13,6),
    E(27,17,0,6), E(28,17,6,6), E(29,17,12,6),
    E(24,16,0,6), E(25,16,6,6),
    E(17,12,7,6), E(14,11,0,6), E(15,11,6,6), E(12,10,0,6), E(5,5,0,6),
    // len 5 (6)
    E(26,16,12,5), E(13,10,6,5), E(10,9,0,5), E(11,9,5,5),
    E(8,8,0,5), E(4,4,0,5),
    // len 4 (2)
    E(9,8,5,4), E(3,3,0,4),
    // len 3,2,1
    E(2,2,0,3), E(1,1,0,2), E(0,0,0,1)
  };
  __shared__ __align__(16) ushort lk[2][64 * 64];    // 16 KB
  __shared__ __align__(16) ushort lv[2][64 * 64];    // 16 KB
  const int t = threadIdx.x;
  const int lane = t & 63, w = t >> 6;
  const int bid = blockIdx.x;
  const int combo = bid & 31;
  const unsigned e = LUT[bid >> 5];
  const int slot = e & 255;
  const int tile = (e >> 8) & 31;
  const int kb0 = (e >> 16) & 31;
  const int len = (int)(e >> 24);

  const int xcd = combo & 7, g = (combo >> 3) & 3;
  const int b = xcd >> 2, kv = xcd & 3, h = kv * 4 + g;
  const int l15 = lane & 15, lg = lane >> 4;
  const int q0 = tile * 64 + w * 16;
  const int t3 = t >> 3, tc8 = t & 7;
  const int rx = l15 & 7;
  const bool odd = (lg & 1);

  const size_t qoff = (((size_t)(b * NH + h)) * TSEQ + q0 + l15) * HDIM;
  bf8v bq0h = *(const bf8v*)(qhi + qoff + lg * 8);
  bf8v bq1h = *(const bf8v*)(qhi + qoff + 32 + lg * 8);
  bf8v bq0l = *(const bf8v*)(qlo + qoff + lg * 8);
  bf8v bq1l = *(const bf8v*)(qlo + qoff + 32 + lg * 8);

  const ushort* kb = kb16 + (size_t)(b * NKV + kv) * TSEQ * 64;
  const ushort* vb = vt2 + (size_t)(b * NKV + kv) * TSEQ * 64;

#define STAGE(BUF, KT) do { \
    _Pragma("unroll") \
    for (int i = 0; i < 2; ++i) { \
      int row = i * 32 + t3; \
      int sc = tc8 ^ (row & 7); \
      GLD16(kb + (size_t)((KT) * 64 + row) * 64 + sc * 8, \
            &lk[BUF][(i * 32 + (w << 3)) * 64]); \
      GLD16(vb + (size_t)(KT) * 4096 + row * 64 + sc * 8, \
            &lv[BUF][(i * 32 + (w << 3)) * 64]); \
    } } while (0)

  STAGE(0, kb0);

  f4v y[4] = {};
  f4v lsum = {};
  float mrow = 0.f;
  const short ob16 = (short)0x3F80;      // bf16 1.0
  const bf8v onesv = { ob16, ob16, ob16, ob16, ob16, ob16, ob16, ob16 };

#pragma unroll 1
  for (int itc = 0; itc < len; ++itc) {
    const int cur = itc & 1;
    const int kt = kb0 + itc;
    __syncthreads();                       // drains prefetch of buf[cur]
    if (itc + 1 < len) STAGE(cur ^ 1, kt + 1);  // flies under this compute

    const ushort* lkc = &lk[cur][0];
    const ushort* lvc = &lv[cur][0];
    const int kv0 = kt * 64;

    // QK: kh*(qh+ql); C-init = -mrow so scores arrive pre-subtracted
    f4v s4[4];
    const f4v zi = { -mrow, -mrow, -mrow, -mrow };
    __builtin_amdgcn_s_setprio(1);
#pragma unroll
    for (int n = 0; n < 4; ++n) {
      const ushort* krow = lkc + (n * 16 + l15) * 64;
      bf8v kh0 = *(const bf8v*)&krow[((0 + lg) ^ rx) * 8];
      bf8v kh1 = *(const bf8v*)&krow[((4 + lg) ^ rx) * 8];
      f4v acc = MFMA16(kh0, bq0h, zi);
      acc = MFMA16(kh1, bq1h, acc);
      acc = MFMA16(kh0, bq0l, acc);
      acc = MFMA16(kh1, bq1l, acc);
      s4[n] = acc;
    }
    __builtin_amdgcn_s_setprio(0);

    // mask + per-lane max; lane holds (S-mrow)^T[key][q=q0+l15]
    const bool need_mask = (kt == tile);
    float mloc = -1e30f;
#pragma unroll
    for (int n = 0; n < 4; ++n)
#pragma unroll
      for (int j = 0; j < 4; ++j) {
        float v = s4[n][j];
        if (need_mask && (kv0 + n * 16 + lg * 4 + j > q0 + l15)) v = -1e30f;
        s4[n][j] = v;
        mloc = fmaxf(mloc, v);
      }
    // vote first (VCC only); cross-lane reduce + adjust only on trigger
    if (__any(mloc > 11.5f)) {
      float mf = fmaxf(mloc, __shfl_xor(mloc, 16));
      mf = fmaxf(mf, __shfl_xor(mf, 32));
      float delta = fmaxf(mf, 0.f);
      float scf = exp2f(-delta);
      lsum *= scf;
#pragma unroll
      for (int n = 0; n < 4; ++n) y[n] *= scf;
#pragma unroll
      for (int n = 0; n < 4; ++n)
#pragma unroll
        for (int j = 0; j < 4; ++j) s4[n][j] -= delta;
      mrow += delta;
    }
#pragma unroll
    for (int n = 0; n < 4; ++n)
#pragma unroll
      for (int j = 0; j < 4; ++j)
        s4[n][j] = exp2f(s4[n][j]);       // arg <= 11.5 by vote invariant

    // ---- in-register P^T redistribution (no LDS, no barrier) ----
    unsigned d0a = cvtpk(s4[0][0], s4[0][1]), d0b = cvtpk(s4[0][2], s4[0][3]);
    unsigned d1a = cvtpk(s4[1][0], s4[1][1]), d1b = cvtpk(s4[1][2], s4[1][3]);
    unsigned d2a = cvtpk(s4[2][0], s4[2][1]), d2b = cvtpk(s4[2][2], s4[2][3]);
    unsigned d3a = cvtpk(s4[3][0], s4[3][1]), d3b = cvtpk(s4[3][2], s4[3][3]);
    asm("v_permlane32_swap_b32 %0, %1" : "+v"(d0a), "+v"(d1a));
    asm("v_permlane32_swap_b32 %0, %1" : "+v"(d0b), "+v"(d1b));
    asm("v_permlane32_swap_b32 %0, %1" : "+v"(d2a), "+v"(d3a));
    asm("v_permlane32_swap_b32 %0, %1" : "+v"(d2b), "+v"(d3b));
    unsigned sa0 = (unsigned)__shfl_xor((int)d0a, 16);
    unsigned sb0 = (unsigned)__shfl_xor((int)d1a, 16);
    unsigned sa1 = (unsigned)__shfl_xor((int)d0b, 16);
    unsigned sb1 = (unsigned)__shfl_xor((int)d1b, 16);
    unsigned sa2 = (unsigned)__shfl_xor((int)d2a, 16);
    unsigned sb2 = (unsigned)__shfl_xor((int)d3a, 16);
    unsigned sa3 = (unsigned)__shfl_xor((int)d2b, 16);
    unsigned sb3 = (unsigned)__shfl_xor((int)d3b, 16);
    u4v u0 = { odd ? sb0 : d0a, odd ? sb1 : d0b,
               odd ? d1a : sa0, odd ? d1b : sa1 };
    u4v u1 = { odd ? sb2 : d2a, odd ? sb3 : d2b,
               odd ? d3a : sa2, odd ? d3b : sa3 };
    bf8v pb0 = __builtin_bit_cast(bf8v, u0);
    bf8v pb1 = __builtin_bit_cast(bf8v, u1);

    __builtin_amdgcn_s_setprio(1);
#pragma unroll
    for (int n = 0; n < 4; ++n) {
      const ushort* vrow = lvc + (n * 16 + l15) * 64;
      bf8v va0 = *(const bf8v*)&vrow[((0 + lg) ^ rx) * 8];
      bf8v va1 = *(const bf8v*)&vrow[((4 + lg) ^ rx) * 8];
      y[n] = MFMA16(va0, pb0, y[n]);
      y[n] = MFMA16(va1, pb1, y[n]);
    }
    lsum = MFMA16(onesv, pb0, lsum);     // row-sum on the MFMA pipe
    lsum = MFMA16(onesv, pb1, lsum);
    __builtin_amdgcn_s_setprio(0);
  }
#undef STAGE

  // epilogue: lrow = lsum[0] (all C-regs equal per column; no shuffles);
  // write unnormalized y partial bf16 [q][64] + m,l
  {
    const float lrow = lsum[0];
    const int pslot = combo * 80 + slot;
    ushort* pb = pyb + (size_t)pslot * 4096;
    const int q = w * 16 + l15;
#pragma unroll
    for (int n = 0; n < 4; ++n) {
      uint2 pk;
      pk.x = cvtpk(y[n][0], y[n][1]);
      pk.y = cvtpk(y[n][2], y[n][3]);
      *(uint2*)&pb[q * 64 + n * 16 + lg * 4] = pk;
    }
    if (lane < 16) {
      float* mlp = pml + (size_t)pslot * 128;
      mlp[q] = mrow;
      mlp[64 + q] = lrow;
    }
  }
}
#undef E

// -------- combine: merge chunk partials, normalize, v-hat removal --------
__global__ __launch_bounds__(256) void combine_kern(
    const ushort* __restrict__ pyb, const float* __restrict__ pml,
    const ushort* __restrict__ vhat_q, ushort* __restrict__ ytil) {
  const int bid = blockIdx.x;
  const int combo = bid & 31, tile = bid >> 5;
  const int xcd = combo & 7, g = (combo >> 3) & 3;
  const int b = xcd >> 2, kv = xcd & 3, h = kv * 4 + g;
  const int nch = (tile + 8) >> 3;
  const int sb = (tile < 8) ? tile
               : (tile < 16) ? 8 + ((tile - 8) << 1)
               : (tile < 24) ? 24 + 3 * (tile - 16)
                             : 48 + ((tile - 24) << 2);
  const int tid = threadIdx.x;
  const int q = tid >> 2, ds = (tid & 3) * 16;
  const int q0 = tile * 64;

  float m[4], l[4];
#pragma unroll
  for (int ci = 0; ci < 4; ++ci) {
    if (ci < nch) {
      const float* mlp = pml + (size_t)(combo * 80 + sb + ci) * 128;
      m[ci] = mlp[q];
      l[ci] = mlp[64 + q];
    } else { m[ci] = -1e30f; l[ci] = 0.f; }
  }
  float M = fmaxf(fmaxf(m[0], m[1]), fmaxf(m[2], m[3]));
  float y[16] = {};
  float ltot = 0.f;
#pragma unroll
  for (int ci = 0; ci < 4; ++ci) {
    if (ci < nch) {
      float sc = exp2f(m[ci] - M);
      ltot += l[ci] * sc;
      const ushort* pb = pyb + (size_t)(combo * 80 + sb + ci) * 4096 + q * 64 + ds;
      bf8v p0 = *(const bf8v*)pb;
      bf8v p1 = *(const bf8v*)(pb + 8);
#pragma unroll
      for (int dd = 0; dd < 8; ++dd) {
        y[dd] += sc * bf2f((ushort)p0[dd]);
        y[8 + dd] += sc * bf2f((ushort)p1[dd]);
      }
    }
  }
  float inv = 1.0f / fmaxf(ltot, 1e-37f);   // guard degenerate rows
  const ushort* vh = vhat_q + ((size_t)(b * NKV + kv) * TSEQ + q0 + q) * 64 + ds;
  bf8v v0 = *(const bf8v*)vh;
  bf8v v1 = *(const bf8v*)(vh + 8);
  float vv[16];
  float dp = 0.f;
#pragma unroll
  for (int dd = 0; dd < 8; ++dd) {
    vv[dd] = bf2f((ushort)v0[dd]);
    vv[8 + dd] = bf2f((ushort)v1[dd]);
  }
#pragma unroll
  for (int dd = 0; dd < 16; ++dd) {
    y[dd] *= inv;
    dp += y[dd] * vv[dd];
  }
  dp += __shfl_xor(dp, 1);
  dp += __shfl_xor(dp, 2);
  bf8v o0, o1;
#pragma unroll
  for (int dd = 0; dd < 8; ++dd) {
    o0[dd] = (short)f2bf(y[dd] - dp * vv[dd]);
    o1[dd] = (short)f2bf(y[8 + dd] - dp * vv[8 + dd]);
  }
  ushort* yo = ytil + ((size_t)(b * TSEQ + q0 + q)) * DIMC + h * HDIM + ds;
  *(bf8v*)yo = o0;
  *(bf8v*)(yo + 8) = o1;
}

extern "C" void kernel_launch(void* const* d_in, const int* in_sizes, int n_in,
                              void* d_out, int out_size, void* d_ws, size_t ws_size,
                              hipStream_t stream) {
  (void)in_sizes; (void)n_in; (void)out_size; (void)ws_size;
  const float* x  = (const float*)d_in[0];
  const float* Wq = (const float*)d_in[1];
  const float* Wk = (const float*)d_in[2];
  const float* Wv = (const float*)d_in[3];
  const float* Wp = (const float*)d_in[4];
  const float* qg = (const float*)d_in[5];
  float* out = (float*)d_out;
  char* ws = (char*)d_ws;
  const size_t KB = 1024, MB = 1ull << 20;

  ushort* xhi = (ushort*)(ws);                         // 8 MiB -> qhi
  ushort* xlo = (ushort*)(ws + 8 * MB);                // 8 MiB -> qlo
  ushort* xb  = (ushort*)(ws + 16 * MB);               // 8 MiB -> ytil
  ushort* wqkh = (ushort*)(ws + 24 * MB);              // 2.5 MiB (Wq|Wk hi)
  ushort* wqkl = (ushort*)(ws + 26 * MB + 512 * KB);   // 2.5 MiB (Wq|Wk lo)
  ushort* wvb = (ushort*)(ws + 29 * MB);               // 0.5 MiB
  ushort* wpb = (ushort*)(ws + 29 * MB + 512 * KB);    // 2 MiB
  float*  cosT = (float*)(ws + 31 * MB + 512 * KB);    // 0.25 MiB
  float*  sinT = (float*)(ws + 31 * MB + 768 * KB);    // 0.25 MiB
  float*  QKf  = (float*)(ws + 32 * MB);               // 20 MiB [4096][1280]
  ushort* kb16 = (ushort*)(ws + 52 * MB);              // 2 MiB
  ushort* vt2  = (ushort*)(ws + 54 * MB);              // 2 MiB

  float*  Vf   = out;                            // d_out: 4 MiB (V f32)
  ushort* QKc  = (ushort*)((char*)out + 4 * MB); // d_out: 10 MiB bf16
  ushort* vhat_q = (ushort*)((char*)out + 14 * MB); // d_out: 2 MiB
  ushort* qhb  = xhi;    // reuse after projections
  ushort* qlb  = xlo;
  ushort* ytil = xb;
  // chunk partials overlay dead QKf: 2560*8KB = 20 MiB; ml at 56MB
  ushort* pyb = (ushort*)(ws + 32 * MB);
  float*  pml = (float*)(ws + 56 * MB);          // 2560*512B = 1.25 MiB

  prep_all<<<6912, 256, 0, stream>>>(x, Wq, Wk, Wv, Wp, xhi, xlo, xb,
                                     wqkh, wqkl, wvb, wpb, cosT, sinT);

  gemm_qkv<<<704, 256, 0, stream>>>(xhi, xlo, wqkh, wqkl, QKf, QKc,
                                    xb, wvb, Vf);

  post_all<<<4352, 256, 0, stream>>>(QKf, QKc, cosT, sinT, qg, qhb, qlb, kb16,
                                     Vf, vt2, vhat_q);
  attn_chunk<<<2560, 256, 0, stream>>>(qhb, qlb, kb16, vt2, pyb, pml);
  combine_kern<<<1024, 256, 0, stream>>>(pyb, pml, vhat_q, ytil);
  gemm_bt<<<dim3(16, 64), 256, 0, stream>>>(ytil, wpb, out, 1024);
}